// Round 1
// baseline (89.744 us; speedup 1.0000x reference)
//
#include <hip/hip_runtime.h>
#include <math.h>

// FractalFeatureLayer: Petrosian-style fractal dimension over 5 dyadic scales.
// x: (B=64, C=64, T=4096) fp32 -> out: (B, C, 57) fp32.
//
// zc per window = range-sum of indicator c[i] = ((x[i+1]-x[i])*(x[i+2]-x[i+1]) < 0),
// window boundaries all multiples of 128 -> 128-wide segment sums + prefix,
// with <=2 boundary-indicator corrections per window.

constexpr int TLEN = 4096;
constexpr int NW   = 57;   // 1+3+7+15+31 windows

__global__ __launch_bounds__(256) void pfd_kernel(const float* __restrict__ x,
                                                  float* __restrict__ out) {
    __shared__ float xs[TLEN];
    __shared__ int   wc[16][4];   // per-k, per-wave popcounts (64 contiguous indicators each)
    __shared__ int   pseg[33];    // exclusive prefix over 32 segments of 128 indicators

    const int tid = threadIdx.x;
    const int row = blockIdx.x;          // flattened (b*C + c)
    const size_t base = (size_t)row * TLEN;

    // ---- coalesced global -> LDS (float4, 16 KB/row) ----
    const float4* xv = reinterpret_cast<const float4*>(x + base);
    float4* sv = reinterpret_cast<float4*>(xs);
#pragma unroll
    for (int m = 0; m < 4; ++m)
        sv[tid + 256 * m] = xv[tid + 256 * m];
    __syncthreads();

    const int wave = tid >> 6;
    const int lane = tid & 63;

    // ---- indicators, thread-strided (stride-1 LDS reads; wave = contiguous 64-block) ----
#pragma unroll
    for (int k = 0; k < 16; ++k) {
        const int i = (k << 8) + tid;    // indicator index
        bool pred = false;
        if (i <= TLEN - 3) {             // valid indicators: 0 .. T-3
            const float a = xs[i];
            const float b = xs[i + 1];
            const float c = xs[i + 2];
            const float d0 = b - a;
            const float d1 = c - b;
            pred = (d0 * d1 < 0.0f);     // exact float32 semantics as reference
        }
        const unsigned long long m = __ballot(pred);
        if (lane == 0) wc[k][wave] = __popcll(m);
    }
    __syncthreads();

    // ---- 33-entry exclusive prefix over 128-wide segments (thread 0, trivial) ----
    if (tid == 0) {
        int acc = 0;
        pseg[0] = 0;
#pragma unroll
        for (int k = 0; k < 16; ++k) {
            acc += wc[k][0] + wc[k][1];  // segment 2k   = indicators [256k,      256k+128)
            pseg[2 * k + 1] = acc;
            acc += wc[k][2] + wc[k][3];  // segment 2k+1 = indicators [256k+128,  256k+256)
            pseg[2 * k + 2] = acc;
        }
    }
    __syncthreads();

    // ---- 57 windows: zc via prefix lookups + boundary corrections, then the log formula ----
    if (tid < NW) {
        int scale, off;
        if (tid < 1)       { scale = 0; off = 0;  }
        else if (tid < 4)  { scale = 1; off = 1;  }
        else if (tid < 11) { scale = 2; off = 4;  }
        else if (tid < 26) { scale = 3; off = 11; }
        else               { scale = 4; off = 26; }
        const int w      = TLEN >> scale;       // 4096,2048,1024,512,256
        const int stride = w >> 1;
        const int s      = (tid - off) * stride;
        const int e      = s + w;               // exclusive end, multiple of 128

        // prefix gives sum c[s .. e-1]; window needs sum c[s .. e-3]
        int zc = pseg[e >> 7] - pseg[s >> 7];
        if (e < TLEN) {                          // c[e-2], c[e-1] exist only then
            const float x0 = xs[e - 2], x1 = xs[e - 1], x2 = xs[e], x3 = xs[e + 1];
            const float d0 = x1 - x0, d1 = x2 - x1, d2 = x3 - x2;
            zc -= (d0 * d1 < 0.0f) ? 1 : 0;
            zc -= (d1 * d2 < 0.0f) ? 1 : 0;
        }

        const float wf  = (float)w;
        const float num = log10f(wf);
        const float den = num + log10f(wf / (wf + 0.4f * (float)zc));
        out[(size_t)row * NW + tid] = num / den;
    }
}

extern "C" void kernel_launch(void* const* d_in, const int* in_sizes, int n_in,
                              void* d_out, int out_size, void* d_ws, size_t ws_size,
                              hipStream_t stream) {
    const float* x = (const float*)d_in[0];
    float* out = (float*)d_out;
    const int rows = in_sizes[0] / TLEN;         // B*C = 4096
    pfd_kernel<<<dim3(rows), dim3(256), 0, stream>>>(x, out);
}